// Round 13
// baseline (988.499 us; speedup 1.0000x reference)
//
#include <hip/hip_runtime.h>
#include <stdint.h>

#define NROWS 32768
#define KC 1024
#define DM 512
#define NKPROD 33554432u   // NROWS*KC
#define NHELP 256          // gemm-worker blocks
#define LDK 40             // padded BK stride in f16 (80 B, 16B-aligned)

typedef _Float16 v8h __attribute__((ext_vector_type(8)));
typedef float v4f __attribute__((ext_vector_type(4)));

// ---------------- threefry2x32 (JAX-exact, key = (0, 42)) ----------------
__device__ __forceinline__ uint32_t rotl32(uint32_t x, int d) {
  return __builtin_amdgcn_alignbit(x, x, 32 - d);   // v_alignbit_b32: 1 inst
}

// Two independent chains (x0=0), ops interleaved 2-wide; returns o0^o1.
__device__ __forceinline__ void threefry_x2(uint32_t xa, uint32_t xb,
                                            uint32_t& oa, uint32_t& ob) {
  const uint32_t ks1 = 42u, ks2 = 0x1BD11BF0u;  // ks0=0; ks2=0^42^0x1BD11BDA
  uint32_t a0 = 0u, a1 = xa + ks1;
  uint32_t b0 = 0u, b1 = xb + ks1;
#define R2(r) { a0 += a1; b0 += b1; a1 = rotl32(a1, r); b1 = rotl32(b1, r); a1 ^= a0; b1 ^= b0; }
  R2(13) R2(15) R2(26) R2(6)
  a0 += ks1; b0 += ks1; a1 += ks2 + 1u; b1 += ks2 + 1u;
  R2(17) R2(29) R2(16) R2(24)
  a0 += ks2; b0 += ks2; a1 += 2u; b1 += 2u;
  R2(13) R2(15) R2(26) R2(6)
  a1 += ks1 + 3u; b1 += ks1 + 3u;                    // a0 += ks0(0)
  R2(17) R2(29) R2(16) R2(24)
  a0 += ks1; b0 += ks1; a1 += ks2 + 4u; b1 += ks2 + 4u;
  R2(13) R2(15) R2(26) R2(6)
  a0 += ks2; b0 += ks2; a1 += 5u; b1 += 5u;
#undef R2
  oa = a0 ^ a1;
  ob = b0 ^ b1;
}

// ---------------- count (+dtype detect) [blocks 0..63] + B split [64..319] ----------------
__global__ __launch_bounds__(256) void k_count_bsplit(
    const uint8_t* __restrict__ mb, const float* __restrict__ B,
    uint32_t* __restrict__ flag, int* __restrict__ cntB, int* __restrict__ cntI,
    _Float16* __restrict__ Bh2, _Float16* __restrict__ Bl2, float* __restrict__ Bn) {
  if (blockIdx.x >= 64) {
    int k = (blockIdx.x - 64) * 4 + (threadIdx.x >> 6);
    int l = threadIdx.x & 63;
    const float* bp = B + (size_t)k * DM + l * 8;
    float x[8];
    *(float4*)&x[0] = *(const float4*)bp;
    *(float4*)&x[4] = *(const float4*)(bp + 4);
    _Float16 h[8], lo[8];
    float s = 0.f;
#pragma unroll
    for (int i = 0; i < 8; ++i) {
      _Float16 hh = (_Float16)x[i];
      h[i] = hh; lo[i] = (_Float16)(x[i] - (float)hh);
      s = fmaf(x[i], x[i], s);
    }
    *(v8h*)&Bh2[(size_t)k * DM + l * 8] = *(v8h*)h;
    *(v8h*)&Bl2[(size_t)k * DM + l * 8] = *(v8h*)lo;
#pragma unroll
    for (int off = 32; off; off >>= 1) s += __shfl_xor(s, off, 64);
    if (l == 0) Bn[k] = s;
    return;
  }
  __shared__ int sB[256], sI[256];
  int t = threadIdx.x, b = blockIdx.x;
  int T = b * 256 + t;
  uint32_t f = 0;
#pragma unroll
  for (int i = 0; i < 2; ++i) {
    int bi = T * 2 + i;
    if ((bi & 3) && mb[bi]) f = 1;   // nonzero high byte => 1-byte bool layout
  }
  if (f) atomicOr(flag, 1u);
  const int* mi = (const int*)mb;
  int r0 = b * 512 + t * 2;
  int cB = 0, cI = 0;
#pragma unroll
  for (int i = 0; i < 2; ++i) {
    int r = r0 + i;
    cB += (mb[r] == 0) ? 1 : 0;
    cI += (mi[r] == 0) ? 1 : 0;
  }
  sB[t] = cB; sI[t] = cI;
  __syncthreads();
  for (int off = 128; off; off >>= 1) {
    if (t < off) { sB[t] += sB[t + off]; sI[t] += sI[t + off]; }
    __syncthreads();
  }
  if (t == 0) { cntB[b] = sB[0]; cntI[b] = sI[0]; }
}

// ---------------- parallel compaction: scatter (order-preserving) ----------------
// idx[0..NP) = non-pad rows ascending; idx[NP..32768) = pad rows ascending.
__global__ __launch_bounds__(256) void k_scatter(const uint8_t* __restrict__ mb,
                                                 const uint32_t* __restrict__ flag,
                                                 const int* __restrict__ cntB,
                                                 const int* __restrict__ cntI,
                                                 int* __restrict__ idx,
                                                 int* __restrict__ npp) {
  __shared__ int sc[256];
  int t = threadIdx.x, b = blockIdx.x;
  bool isbool = (*flag) != 0;
  const int* mi = (const int*)mb;
  const int* cnt = isbool ? cntB : cntI;
  int pre = 0, tot = 0;
  for (int j = 0; j < 64; ++j) {
    int c = cnt[j];
    if (j < b) pre += c;
    tot += c;
  }
  int r0 = b * 512 + t * 2;
  bool np0 = isbool ? (mb[r0] == 0)     : (mi[r0] == 0);
  bool np1 = isbool ? (mb[r0 + 1] == 0) : (mi[r0 + 1] == 0);
  int my = (int)np0 + (int)np1;
  sc[t] = my;
  __syncthreads();
  for (int off = 1; off < 256; off <<= 1) {
    int v = (t >= off) ? sc[t - off] : 0;
    __syncthreads();
    sc[t] += v;
    __syncthreads();
  }
  int excl = sc[t] - my;                 // nonpad rows before this thread in block
  int npPos = pre + excl;
  int padPos = tot + (b * 512 - pre) + (t * 2 - excl);
  if (np0) idx[npPos++] = r0;     else idx[padPos++] = r0;
  if (np1) idx[npPos]   = r0 + 1; else idx[padPos]   = r0 + 1;
  if (b == 0 && t == 0) *npp = tot;
}

// ---------------- MEGA: gemm workers + pad workers -> shared sampling pool ----------------
// Blocks [0,NHELP): ticket-loop gemm tiles (in-kernel A split), flag per 128-row group.
// Blocks [NHELP,1024): pad tickets (fills gemm ramp), then all blocks sample with
// per-group spin. Grid=1024 = guaranteed full residency (LDS 40KB, VGPR<=128) =>
// spin-wait is deadlock-free under any dispatch order.
__global__ __launch_bounds__(256, 4) void k_mega(
    const float* __restrict__ X, const float* __restrict__ CW,
    const _Float16* __restrict__ Bh2, const _Float16* __restrict__ Bl2,
    const float* __restrict__ Bn,
    const int* __restrict__ idx, const int* __restrict__ npp,
    float* __restrict__ S, float* __restrict__ qout,
    float* __restrict__ cnt, double* __restrict__ esum,
    int* __restrict__ gc, int* __restrict__ pc, int* __restrict__ scc,
    int* __restrict__ gemmDone) {
  __shared__ _Float16 AhS[128 * LDK], AlS[128 * LDK];
  __shared__ _Float16 BhS[128 * LDK], BlS[128 * LDK];
  __shared__ int sticket;
  int NP = *npp;
  int ngroups = (NP + 127) >> 7;
  int NTG = ngroups << 3;
  int NPAD = NROWS - NP;
  int NTP = (NPAD + 15) >> 4;
  int NTS = (NP + 3) >> 2;
  int tid = threadIdx.x;
  int wid = tid >> 6, l = tid & 63;

  if (blockIdx.x < NHELP) {
    // ================= gemm worker =================
    int wr = wid >> 1, wc = wid & 1;
    int lr = l & 15, k8 = (l >> 4) * 8;
    int srow = tid >> 1, ssub = (tid & 1) * 16;
    while (true) {
      __syncthreads();
      if (tid == 0) sticket = atomicAdd(gc, 1);
      __syncthreads();
      int g = sticket;
      if (g >= NTG) break;
      int by = g >> 3, bx = g & 7;
      int r0 = by << 7, c0 = bx << 7;
      int orig = idx[r0 + srow];
      const float* ag = X + (size_t)orig * DM + ssub;
      const _Float16* bhg = Bh2 + (size_t)(c0 + srow) * DM + ssub;
      const _Float16* blg = Bl2 + (size_t)(c0 + srow) * DM + ssub;

      v4f acc[4][4];
#pragma unroll
      for (int m = 0; m < 4; ++m)
#pragma unroll
        for (int n = 0; n < 4; ++n) acc[m][n] = (v4f)0.0f;
      float sqa = 0.f;

      for (int k0 = 0; k0 < DM; k0 += 32) {
        float xa[16];
#pragma unroll
        for (int i = 0; i < 16; i += 4)
          *(float4*)&xa[i] = *(const float4*)(ag + k0 + i);
        v8h bh0 = *(const v8h*)(bhg + k0);
        v8h bh1 = *(const v8h*)(bhg + k0 + 8);
        v8h bl0 = *(const v8h*)(blg + k0);
        v8h bl1 = *(const v8h*)(blg + k0 + 8);
        _Float16 ha[16], la[16];
#pragma unroll
        for (int i = 0; i < 16; ++i) {
          float x = xa[i];
          _Float16 h = (_Float16)x;
          ha[i] = h; la[i] = (_Float16)(x - (float)h);
          sqa = fmaf(x, x, sqa);
        }
        __syncthreads();   // previous iter's frag reads done
        int wb = srow * LDK + ssub;
        *(v8h*)&AhS[wb]     = *(v8h*)&ha[0];
        *(v8h*)&AhS[wb + 8] = *(v8h*)&ha[8];
        *(v8h*)&AlS[wb]     = *(v8h*)&la[0];
        *(v8h*)&AlS[wb + 8] = *(v8h*)&la[8];
        *(v8h*)&BhS[wb]     = bh0;
        *(v8h*)&BhS[wb + 8] = bh1;
        *(v8h*)&BlS[wb]     = bl0;
        *(v8h*)&BlS[wb + 8] = bl1;
        __syncthreads();

        v8h fah[4], fal[4];
#pragma unroll
        for (int m = 0; m < 4; ++m) {
          int row = wr * 64 + m * 16 + lr;
          fah[m] = *(const v8h*)&AhS[row * LDK + k8];
          fal[m] = *(const v8h*)&AlS[row * LDK + k8];
        }
#pragma unroll
        for (int n = 0; n < 4; ++n) {
          int col = wc * 64 + n * 16 + lr;
          v8h fbh = *(const v8h*)&BhS[col * LDK + k8];
          v8h fbl = *(const v8h*)&BlS[col * LDK + k8];
#pragma unroll
          for (int m = 0; m < 4; ++m) {
            acc[m][n] = __builtin_amdgcn_mfma_f32_16x16x32_f16(fah[m], fbh, acc[m][n], 0, 0, 0);
            acc[m][n] = __builtin_amdgcn_mfma_f32_16x16x32_f16(fah[m], fbl, acc[m][n], 0, 0, 0);
            acc[m][n] = __builtin_amdgcn_mfma_f32_16x16x32_f16(fal[m], fbh, acc[m][n], 0, 0, 0);
          }
        }
      }

      // A-row norms via LDS-buffer reuse (keeps total LDS at 40 KB)
      __syncthreads();                   // all frag reads done
      float* tmpf = (float*)AhS;         // 1 KB scratch
      float* rsf  = (float*)AlS;         // 512 B
      tmpf[tid] = sqa;
      __syncthreads();
      if ((tid & 1) == 0) rsf[srow] = tmpf[tid] + tmpf[tid + 1];
      __syncthreads();

      float cnp[4];
#pragma unroll
      for (int n = 0; n < 4; ++n) cnp[n] = Bn[c0 + wc * 64 + n * 16 + lr];

#pragma unroll
      for (int m = 0; m < 4; ++m) {
        int rl = wr * 64 + m * 16 + (l >> 4) * 4;
#pragma unroll
        for (int r = 0; r < 4; ++r) {
          int sl = r0 + rl + r;
          if (sl < NP) {                 // pad tail rows owned by pad workers
            int org = idx[sl];
            float rq = rsf[rl + r];
            float* sp = S + (size_t)org * KC + c0;
#pragma unroll
            for (int n = 0; n < 4; ++n) {
              int cl = wc * 64 + n * 16 + lr;
              sp[cl] = -((rq + cnp[n]) - 2.0f * acc[m][n][r]);
            }
          }
        }
      }
      __threadfence();
      __syncthreads();
      if (tid == 0) atomicAdd(&gemmDone[by], 1);
    }
  } else {
    // ================= pad worker =================
    while (true) {
      __syncthreads();
      if (tid == 0) sticket = atomicAdd(pc, 1);
      __syncthreads();
      int p = sticket;
      if (p >= NTP) break;
      for (int i = 0; i < 4; ++i) {
        int ps = (p << 4) + (wid << 2) + i;
        if (ps >= NPAD) break;
        int n = idx[NP + ps];
        float* so = S + (size_t)n * KC + l * 16;
        float4 z = make_float4(0.f, 0.f, 0.f, 0.f);
        *(float4*)(so)      = (l == 0) ? make_float4(10.f, 0.f, 0.f, 0.f) : z;
        *(float4*)(so + 4)  = z;
        *(float4*)(so + 8)  = z;
        *(float4*)(so + 12) = z;
        const float* xr = X + (size_t)n * DM + l * 8;
        float4 x0 = *(const float4*)xr, x1 = *(const float4*)(xr + 4);
        float* qo = qout + (size_t)n * DM + l * 8;
        *(float4*)qo       = z;
        *(float4*)(qo + 4) = z;
        double ls = (double)(x0.x*x0.x) + (double)(x0.y*x0.y)
                  + (double)(x0.z*x0.z) + (double)(x0.w*x0.w)
                  + (double)(x1.x*x1.x) + (double)(x1.y*x1.y)
                  + (double)(x1.z*x1.z) + (double)(x1.w*x1.w);
#pragma unroll
        for (int off = 32; off; off >>= 1) ls += __shfl_xor(ls, off, 64);
        if (l == 0) atomicAdd(&esum[n & 63], ls);
      }
    }
  }

  // ================= sampling (all blocks) =================
  // Bit-identical draw stream: bits = o0^o1 of threefry(key,(0,t));
  // argmax_k(g_k+l_k) == argmax_k fl(log2(u_k)*m_k), m_k = ln2*exp(lmax-l_k).
  while (true) {
    __syncthreads();
    if (tid == 0) sticket = atomicAdd(scc, 1);
    __syncthreads();
    int st = sticket;
    if (st >= NTS) break;
    int g = (st << 2) >> 7;
    if (tid == 0) {
      while (atomicAdd(&gemmDone[g], 0) < 8) __builtin_amdgcn_s_sleep(32);
    }
    __syncthreads();
    __threadfence();
    int slot = (st << 2) + wid;
    if (slot < NP) {
      int n = idx[slot];
      int base = l * 16;
      const float* srow = S + (size_t)n * KC + base;

      float lmax;
      {
        float lg0[16];
#pragma unroll
        for (int j = 0; j < 16; j += 4)
          *(float4*)&lg0[j] = *(const float4*)(srow + j);
        if (l == 0) lg0[0] = -__builtin_inff();
        lmax = lg0[0];
#pragma unroll
        for (int i = 1; i < 16; ++i) lmax = fmaxf(lmax, lg0[i]);
#pragma unroll
        for (int off = 32; off; off >>= 1)
          lmax = fmaxf(lmax, __shfl_xor(lmax, off, 64));
      }

      float bv[10];
      uint32_t bi[10];
#pragma unroll
      for (int s = 0; s < 10; ++s) { bv[s] = -__builtin_inff(); bi[s] = 0xFFFFFFFFu; }

      uint32_t tb0 = (uint32_t)n * (uint32_t)KC + (uint32_t)base;
#pragma unroll 1
      for (int j = 0; j < 16; ++j) {
        float lgj = srow[j];                 // L1-hot scalar reload
        uint32_t kk = (uint32_t)(base + j);
        if (kk == 0u) lgj = -__builtin_inff();  // code 0 disallowed
        float mj = 0.69314718056f * __expf(lmax - lgj);
        uint32_t t0 = tb0 + (uint32_t)j;
#pragma unroll
        for (int sp = 0; sp < 5; ++sp) {
          uint32_t ba, bb;
          threefry_x2(t0 + (uint32_t)(2 * sp) * NKPROD,
                      t0 + (uint32_t)(2 * sp + 1) * NKPROD, ba, bb);
          float fa = __uint_as_float((ba >> 9) | 0x3F800000u) - 1.0f;
          float fb = __uint_as_float((bb >> 9) | 0x3F800000u) - 1.0f;
          float ua = fmaxf(1.17549435e-38f, fa);
          float ub = fmaxf(1.17549435e-38f, fb);
          float va = __log2f(ua) * mj;
          float vb = __log2f(ub) * mj;
          if (va > bv[2 * sp])     { bv[2 * sp] = va;     bi[2 * sp] = kk; }
          if (vb > bv[2 * sp + 1]) { bv[2 * sp + 1] = vb; bi[2 * sp + 1] = kk; }
        }
      }

#pragma unroll
      for (int s = 0; s < 10; ++s) {
#pragma unroll
        for (int off = 32; off; off >>= 1) {
          float ov = __shfl_xor(bv[s], off, 64);
          uint32_t oi = __shfl_xor(bi[s], off, 64);
          if (ov > bv[s] || (ov == bv[s] && oi < bi[s])) { bv[s] = ov; bi[s] = oi; }
        }
      }

      // counts (overwrites this row's logits)
      float* so = S + (size_t)n * KC + base;
#pragma unroll
      for (int j4 = 0; j4 < 16; j4 += 4) {
        float c[4];
#pragma unroll
        for (int i = 0; i < 4; ++i) {
          uint32_t k = (uint32_t)(base + j4 + i);
          float cc = 0.f;
#pragma unroll
          for (int s = 0; s < 10; ++s) cc += (bi[s] == k) ? 1.f : 0.f;
          c[i] = cc;
        }
        *(float4*)(so + j4) = make_float4(c[0], c[1], c[2], c[3]);
      }

      float q[8];
#pragma unroll
      for (int i = 0; i < 8; ++i) q[i] = 0.f;
#pragma unroll
      for (int s = 0; s < 10; ++s) {
        const float* cr = CW + (size_t)bi[s] * DM + l * 8;
        float4 g0 = *(const float4*)cr;
        float4 g1 = *(const float4*)(cr + 4);
        q[0] += g0.x; q[1] += g0.y; q[2] += g0.z; q[3] += g0.w;
        q[4] += g1.x; q[5] += g1.y; q[6] += g1.z; q[7] += g1.w;
        if (l == 0) atomicAdd(&cnt[bi[s]], 1.0f);
      }

      const float* xr = X + (size_t)n * DM + l * 8;
      float4 x0 = *(const float4*)xr, x1 = *(const float4*)(xr + 4);
      float xs[8] = {x0.x, x0.y, x0.z, x0.w, x1.x, x1.y, x1.z, x1.w};
      float st8[8];
      double ls = 0.0;
#pragma unroll
      for (int j = 0; j < 8; ++j) {
        float qq = q[j] / 10.0f;
        float d = qq - xs[j];
        ls += (double)(d * d);
        st8[j] = xs[j] + d;
      }
      float* qo = qout + (size_t)n * DM + l * 8;
      *(float4*)qo       = make_float4(st8[0], st8[1], st8[2], st8[3]);
      *(float4*)(qo + 4) = make_float4(st8[4], st8[5], st8[6], st8[7]);

#pragma unroll
      for (int off = 32; off; off >>= 1) ls += __shfl_xor(ls, off, 64);
      if (l == 0) atomicAdd(&esum[n & 63], ls);
    }
  }
}

// ---------------- scalars: loss + perplexity ----------------
__global__ __launch_bounds__(256) void k_final(const int* __restrict__ npp,
                                               const float* __restrict__ cnt,
                                               const double* __restrict__ esum,
                                               float* __restrict__ scal) {
  __shared__ double snd[256];
  int t = threadIdx.x;
  int npad = NROWS - *npp;
  double ss = 0.0;
  for (int k = t; k < KC; k += 256) {
    float c = (k == 0) ? (float)(npad * 10) : cnt[k];
    float p = c / 327680.0f;   // / (N * NUM_SAMPLES)
    ss += (double)(p * logf(p + 1e-10f));
  }
  snd[t] = ss;
  __syncthreads();
  for (int off = 128; off; off >>= 1) {
    if (t < off) snd[t] += snd[t + off];
    __syncthreads();
  }
  if (t == 0) {
    double es = 0.0;
    for (int i = 0; i < 64; ++i) es += esum[i];
    float num_nonpad = (float)((NROWS - npad) * DM);
    float el = (float)es / num_nonpad;
    scal[0] = 0.25f * el;               // loss
    scal[1] = expf(-(float)snd[0]);     // perplexity
  }
}

extern "C" void kernel_launch(void* const* d_in, const int* in_sizes, int n_in,
                              void* d_out, int out_size, void* d_ws, size_t ws_size,
                              hipStream_t stream) {
  const float* X  = (const float*)d_in[0];
  const void*  M  = d_in[1];
  const float* CW = (const float*)d_in[2];
  float* out  = (float*)d_out;
  float* qout = out;                    // [0, 16777216): quantized_st
  float* sout = out + 16777216;         // [.., 50331648): logits -> samples
  float* scal = out + 50331648;         // loss, perplexity
  uint8_t* ws = (uint8_t*)d_ws;
  double*   esum = (double*)ws;           // 512 B (64 striped slots)
  uint32_t* flag = (uint32_t*)(ws + 512);
  int*      npp  = (int*)(ws + 768);
  float*    cnt  = (float*)(ws + 1024);   // 4 KB per-code totals
  int*      cntB = (int*)(ws + 5120);     // 256 B
  int*      cntI = (int*)(ws + 5376);     // 256 B
  int*      gc   = (int*)(ws + 5632);     // gemm ticket counter
  int*      pc   = (int*)(ws + 5636);     // pad ticket counter
  int*      scc  = (int*)(ws + 5640);     // sample ticket counter
  int*      gdon = (int*)(ws + 6144);     // 1 KB gemmDone[256]
  int*      idx  = (int*)(ws + 8192);     // 128 KB: nonpad [0,NP) + pad [NP,32768)
  _Float16* Bh2  = (_Float16*)(ws + 139264);            // 1 MiB
  _Float16* Bl2  = (_Float16*)(ws + 139264 + 1048576);  // 1 MiB
  float*    Bn   = (float*)(ws + 139264 + 2097152);     // 4 KB
  (void)in_sizes; (void)n_in; (void)out_size; (void)ws_size;

  hipMemsetAsync(d_ws, 0, 8192, stream);   // esum+flag+npp+cnt+counters+gemmDone
  k_count_bsplit<<<320, 256, 0, stream>>>((const uint8_t*)M, CW, flag, cntB, cntI,
                                          Bh2, Bl2, Bn);
  k_scatter<<<64, 256, 0, stream>>>((const uint8_t*)M, flag, cntB, cntI, idx, npp);
  k_mega<<<1024, 256, 0, stream>>>(X, CW, Bh2, Bl2, Bn, idx, npp,
                                   sout, qout, cnt, esum, gc, pc, scc, gdon);
  k_final<<<1, 256, 0, stream>>>(npp, cnt, esum, scal);
}

// Round 14
// 487.969 us; speedup vs baseline: 2.0257x; 2.0257x over previous
//
#include <hip/hip_runtime.h>
#include <stdint.h>

#define NROWS 32768
#define KC 1024
#define DM 512
#define NKPROD 33554432u   // NROWS*KC

typedef _Float16 v8h __attribute__((ext_vector_type(8)));
typedef float v4f __attribute__((ext_vector_type(4)));

// ---------------- threefry2x32 (JAX-exact, key = (0, 42)) ----------------
__device__ __forceinline__ uint32_t rotl32(uint32_t x, int d) {
  return __builtin_amdgcn_alignbit(x, x, 32 - d);   // v_alignbit_b32: 1 inst
}

// Two independent chains (x0=0), ops interleaved 2-wide; returns o0^o1.
__device__ __forceinline__ void threefry_x2(uint32_t xa, uint32_t xb,
                                            uint32_t& oa, uint32_t& ob) {
  const uint32_t ks1 = 42u, ks2 = 0x1BD11BF0u;  // ks0=0; ks2=0^42^0x1BD11BDA
  uint32_t a0 = 0u, a1 = xa + ks1;
  uint32_t b0 = 0u, b1 = xb + ks1;
#define R2(r) { a0 += a1; b0 += b1; a1 = rotl32(a1, r); b1 = rotl32(b1, r); a1 ^= a0; b1 ^= b0; }
  R2(13) R2(15) R2(26) R2(6)
  a0 += ks1; b0 += ks1; a1 += ks2 + 1u; b1 += ks2 + 1u;
  R2(17) R2(29) R2(16) R2(24)
  a0 += ks2; b0 += ks2; a1 += 2u; b1 += 2u;
  R2(13) R2(15) R2(26) R2(6)
  a1 += ks1 + 3u; b1 += ks1 + 3u;                    // a0 += ks0(0)
  R2(17) R2(29) R2(16) R2(24)
  a0 += ks1; b0 += ks1; a1 += ks2 + 4u; b1 += ks2 + 4u;
  R2(13) R2(15) R2(26) R2(6)
  a0 += ks2; b0 += ks2; a1 += 5u; b1 += 5u;
#undef R2
  oa = a0 ^ a1;
  ob = b0 ^ b1;
}

// ---------------- count (+dtype detect) [blocks 0..63] + B split [64..319] ----------------
__global__ __launch_bounds__(256) void k_count_bsplit(
    const uint8_t* __restrict__ mb, const float* __restrict__ B,
    uint32_t* __restrict__ flag, int* __restrict__ cntB, int* __restrict__ cntI,
    _Float16* __restrict__ Bh2, _Float16* __restrict__ Bl2, float* __restrict__ Bn) {
  if (blockIdx.x >= 64) {
    int k = (blockIdx.x - 64) * 4 + (threadIdx.x >> 6);
    int l = threadIdx.x & 63;
    const float* bp = B + (size_t)k * DM + l * 8;
    float x[8];
    *(float4*)&x[0] = *(const float4*)bp;
    *(float4*)&x[4] = *(const float4*)(bp + 4);
    _Float16 h[8], lo[8];
    float s = 0.f;
#pragma unroll
    for (int i = 0; i < 8; ++i) {
      _Float16 hh = (_Float16)x[i];
      h[i] = hh; lo[i] = (_Float16)(x[i] - (float)hh);
      s = fmaf(x[i], x[i], s);
    }
    *(v8h*)&Bh2[(size_t)k * DM + l * 8] = *(v8h*)h;
    *(v8h*)&Bl2[(size_t)k * DM + l * 8] = *(v8h*)lo;
#pragma unroll
    for (int off = 32; off; off >>= 1) s += __shfl_xor(s, off, 64);
    if (l == 0) Bn[k] = s;
    return;
  }
  __shared__ int sB[256], sI[256];
  int t = threadIdx.x, b = blockIdx.x;
  int T = b * 256 + t;
  uint32_t f = 0;
#pragma unroll
  for (int i = 0; i < 2; ++i) {
    int bi = T * 2 + i;
    if ((bi & 3) && mb[bi]) f = 1;   // nonzero high byte => 1-byte bool layout
  }
  if (f) atomicOr(flag, 1u);
  const int* mi = (const int*)mb;
  int r0 = b * 512 + t * 2;
  int cB = 0, cI = 0;
#pragma unroll
  for (int i = 0; i < 2; ++i) {
    int r = r0 + i;
    cB += (mb[r] == 0) ? 1 : 0;
    cI += (mi[r] == 0) ? 1 : 0;
  }
  sB[t] = cB; sI[t] = cI;
  __syncthreads();
  for (int off = 128; off; off >>= 1) {
    if (t < off) { sB[t] += sB[t + off]; sI[t] += sI[t + off]; }
    __syncthreads();
  }
  if (t == 0) { cntB[b] = sB[0]; cntI[b] = sI[0]; }
}

// ---------------- parallel compaction: scatter (order-preserving) ----------------
// idx[0..NP) = non-pad rows ascending; idx[NP..32768) = pad rows ascending.
__global__ __launch_bounds__(256) void k_scatter(const uint8_t* __restrict__ mb,
                                                 const uint32_t* __restrict__ flag,
                                                 const int* __restrict__ cntB,
                                                 const int* __restrict__ cntI,
                                                 int* __restrict__ idx,
                                                 int* __restrict__ npp) {
  __shared__ int sc[256];
  int t = threadIdx.x, b = blockIdx.x;
  bool isbool = (*flag) != 0;
  const int* mi = (const int*)mb;
  const int* cnt = isbool ? cntB : cntI;
  int pre = 0, tot = 0;
  for (int j = 0; j < 64; ++j) {
    int c = cnt[j];
    if (j < b) pre += c;
    tot += c;
  }
  int r0 = b * 512 + t * 2;
  bool np0 = isbool ? (mb[r0] == 0)     : (mi[r0] == 0);
  bool np1 = isbool ? (mb[r0 + 1] == 0) : (mi[r0 + 1] == 0);
  int my = (int)np0 + (int)np1;
  sc[t] = my;
  __syncthreads();
  for (int off = 1; off < 256; off <<= 1) {
    int v = (t >= off) ? sc[t - off] : 0;
    __syncthreads();
    sc[t] += v;
    __syncthreads();
  }
  int excl = sc[t] - my;                 // nonpad rows before this thread in block
  int npPos = pre + excl;
  int padPos = tot + (b * 512 - pre) + (t * 2 - excl);
  if (np0) idx[npPos++] = r0;     else idx[padPos++] = r0;
  if (np1) idx[npPos]   = r0 + 1; else idx[padPos]   = r0 + 1;
  if (b == 0 && t == 0) *npp = tot;
}

// ---------------- A split (slots < ceil128(NP)) + pad loss/counts ----------------
// slot < NPc: f16 hi/lo split + row norm (gemm staging).
// slot >= NP: loss += ||x||^2. slot >= NPc: also counts row (c0=10) into S.
// (qout zeroing and tail-pad counts rows happen in the sampler, after gemm.)
__global__ __launch_bounds__(256) void k_asplit_pad(
    const float* __restrict__ X, const int* __restrict__ idx,
    const int* __restrict__ npp,
    _Float16* __restrict__ Ah2, _Float16* __restrict__ Al2,
    float* __restrict__ An, float* __restrict__ sout,
    double* __restrict__ esum) {
  int NP = *npp;
  int NPc = (NP + 127) & ~127;
  int slot = blockIdx.x * 4 + (threadIdx.x >> 6);
  int l = threadIdx.x & 63;
  int n = idx[slot];
  const float* xr = X + (size_t)n * DM + l * 8;

  if (slot < NPc) {
    float x[8];
    *(float4*)&x[0] = *(const float4*)xr;
    *(float4*)&x[4] = *(const float4*)(xr + 4);
    _Float16 h[8], lo[8];
    float s = 0.f;
#pragma unroll
    for (int i = 0; i < 8; ++i) {
      _Float16 hh = (_Float16)x[i];
      h[i] = hh; lo[i] = (_Float16)(x[i] - (float)hh);
      s = fmaf(x[i], x[i], s);
    }
    *(v8h*)&Ah2[(size_t)slot * DM + l * 8] = *(v8h*)h;
    *(v8h*)&Al2[(size_t)slot * DM + l * 8] = *(v8h*)lo;
#pragma unroll
    for (int off = 32; off; off >>= 1) s += __shfl_xor(s, off, 64);
    if (l == 0) An[slot] = s;
    if (slot < NP) return;   // non-pad done; tail pads fall through for loss
  }

  // pad: loss
  float4 x0 = *(const float4*)xr, x1 = *(const float4*)(xr + 4);
  double ls = (double)(x0.x*x0.x) + (double)(x0.y*x0.y)
            + (double)(x0.z*x0.z) + (double)(x0.w*x0.w)
            + (double)(x1.x*x1.x) + (double)(x1.y*x1.y)
            + (double)(x1.z*x1.z) + (double)(x1.w*x1.w);
#pragma unroll
  for (int off = 32; off; off >>= 1) ls += __shfl_xor(ls, off, 64);
  if (l == 0) atomicAdd(&esum[n & 63], ls);

  if (slot >= NPc) {
    // far-pad counts row (gemm never touches these S rows)
    float* so = sout + (size_t)n * KC + l * 16;
    float4 z = make_float4(0.f, 0.f, 0.f, 0.f);
    *(float4*)(so)      = (l == 0) ? make_float4(10.f, 0.f, 0.f, 0.f) : z;
    *(float4*)(so + 4)  = z;
    *(float4*)(so + 8)  = z;
    *(float4*)(so + 12) = z;
  }
}

// ---------------- logits GEMM: all operands pre-split, VALU-light K-loop ----------------
#define LDK 40   // padded BK stride in f16 (80 B, 16B-aligned)
__global__ __launch_bounds__(256) void k_gemm5(const _Float16* __restrict__ Ah2,
                                               const _Float16* __restrict__ Al2,
                                               const float* __restrict__ An,
                                               const _Float16* __restrict__ Bh2,
                                               const _Float16* __restrict__ Bl2,
                                               const float* __restrict__ Bn,
                                               const int* __restrict__ idx,
                                               const int* __restrict__ npp,
                                               float* __restrict__ S) {
  int NP = *npp;
  int bx = blockIdx.x & 7;           // N panel
  int by = blockIdx.x >> 3;          // M panel (compact slots)
  int r0 = by * 128, c0 = bx * 128;
  if (r0 >= NP) return;

  __shared__ _Float16 Ah[128 * LDK], Al[128 * LDK];
  __shared__ _Float16 Bh[128 * LDK], Bl[128 * LDK];

  int tid = threadIdx.x;
  int wid = tid >> 6;
  int wr = wid >> 1, wc = wid & 1;   // wave sub-tile (64x64)
  int l = tid & 63;
  int lr = l & 15;
  int k8 = (l >> 4) * 8;

  int srow = tid >> 1;               // staging slot-row 0..127
  int ssub = (tid & 1) * 16;         // staging k sub-offset

  const _Float16* ahg = Ah2 + (size_t)(r0 + srow) * DM + ssub;
  const _Float16* alg = Al2 + (size_t)(r0 + srow) * DM + ssub;
  const _Float16* bhg = Bh2 + (size_t)(c0 + srow) * DM + ssub;
  const _Float16* blg = Bl2 + (size_t)(c0 + srow) * DM + ssub;

  v4f acc[4][4];
#pragma unroll
  for (int m = 0; m < 4; ++m)
#pragma unroll
    for (int n = 0; n < 4; ++n) acc[m][n] = (v4f)0.0f;

  for (int k0 = 0; k0 < DM; k0 += 32) {
    v8h ah0 = *(const v8h*)(ahg + k0);
    v8h ah1 = *(const v8h*)(ahg + k0 + 8);
    v8h al0 = *(const v8h*)(alg + k0);
    v8h al1 = *(const v8h*)(alg + k0 + 8);
    v8h bh0 = *(const v8h*)(bhg + k0);
    v8h bh1 = *(const v8h*)(bhg + k0 + 8);
    v8h bl0 = *(const v8h*)(blg + k0);
    v8h bl1 = *(const v8h*)(blg + k0 + 8);
    __syncthreads();   // previous iter's frag reads done
    int wb = srow * LDK + ssub;
    *(v8h*)&Ah[wb]     = ah0;
    *(v8h*)&Ah[wb + 8] = ah1;
    *(v8h*)&Al[wb]     = al0;
    *(v8h*)&Al[wb + 8] = al1;
    *(v8h*)&Bh[wb]     = bh0;
    *(v8h*)&Bh[wb + 8] = bh1;
    *(v8h*)&Bl[wb]     = bl0;
    *(v8h*)&Bl[wb + 8] = bl1;
    __syncthreads();

    v8h fah[4], fal[4];
#pragma unroll
    for (int m = 0; m < 4; ++m) {
      int row = wr * 64 + m * 16 + lr;
      fah[m] = *(const v8h*)&Ah[row * LDK + k8];
      fal[m] = *(const v8h*)&Al[row * LDK + k8];
    }
#pragma unroll
    for (int n = 0; n < 4; ++n) {
      int col = wc * 64 + n * 16 + lr;
      v8h fbh = *(const v8h*)&Bh[col * LDK + k8];
      v8h fbl = *(const v8h*)&Bl[col * LDK + k8];
#pragma unroll
      for (int m = 0; m < 4; ++m) {
        acc[m][n] = __builtin_amdgcn_mfma_f32_16x16x32_f16(fah[m], fbh, acc[m][n], 0, 0, 0);
        acc[m][n] = __builtin_amdgcn_mfma_f32_16x16x32_f16(fah[m], fbl, acc[m][n], 0, 0, 0);
        acc[m][n] = __builtin_amdgcn_mfma_f32_16x16x32_f16(fal[m], fbh, acc[m][n], 0, 0, 0);
      }
    }
  }

  float cnp[4];
#pragma unroll
  for (int n = 0; n < 4; ++n) cnp[n] = Bn[c0 + wc * 64 + n * 16 + lr];

#pragma unroll
  for (int m = 0; m < 4; ++m) {
    int rl = wr * 64 + m * 16 + (l >> 4) * 4;
#pragma unroll
    for (int r = 0; r < 4; ++r) {
      int org = idx[r0 + rl + r];
      float rq = An[r0 + rl + r];
      float* sp = S + (size_t)org * KC + c0;
#pragma unroll
      for (int n = 0; n < 4; ++n) {
        int cl = wc * 64 + n * 16 + lr;
        sp[cl] = -((rq + cnp[n]) - 2.0f * acc[m][n][r]);
      }
    }
  }
}

// ---------------- sampling (non-pad) + light pad finalize ----------------
// slot < NP: bit-identical draw stream (bits = o0^o1 of threefry(key,(0,t));
// argmax fl(log2(u)*m), m = ln2*exp(lmax-l)).
// slot >= NP: zero qout row; tail slots [NP, NPc) also counts row (over gemm logits).
__global__ __launch_bounds__(256, 8) void k_sample_i(
    const float* __restrict__ S, const float* __restrict__ X,
    const float* __restrict__ CW, const int* __restrict__ idx,
    const int* __restrict__ npp,
    float* __restrict__ qout, float* __restrict__ sout,
    float* __restrict__ cnt, double* __restrict__ esum) {
  int NP = *npp;
  int slot = blockIdx.x * 4 + (threadIdx.x >> 6);
  int l = threadIdx.x & 63;
  int n = idx[slot];
  int base = l * 16;

  if (slot >= NP) {
    // light pad finalize: qout zero (+ tail counts row); then retire
    float4 z = make_float4(0.f, 0.f, 0.f, 0.f);
    float* qo = qout + (size_t)n * DM + l * 8;
    *(float4*)qo       = z;
    *(float4*)(qo + 4) = z;
    int NPc = (NP + 127) & ~127;
    if (slot < NPc) {
      float* so = sout + (size_t)n * KC + base;
      *(float4*)(so)      = (l == 0) ? make_float4(10.f, 0.f, 0.f, 0.f) : z;
      *(float4*)(so + 4)  = z;
      *(float4*)(so + 8)  = z;
      *(float4*)(so + 12) = z;
    }
    return;
  }

  const float* srow = S + (size_t)n * KC + base;

  // row max (transient lg regs)
  float lmax;
  {
    float lg0[16];
#pragma unroll
    for (int j = 0; j < 16; j += 4)
      *(float4*)&lg0[j] = *(const float4*)(srow + j);
    if (l == 0) lg0[0] = -__builtin_inff();
    lmax = lg0[0];
#pragma unroll
    for (int i = 1; i < 16; ++i) lmax = fmaxf(lmax, lg0[i]);
#pragma unroll
    for (int off = 32; off; off >>= 1)
      lmax = fmaxf(lmax, __shfl_xor(lmax, off, 64));
  }

  float bv[10];
  uint32_t bi[10];
#pragma unroll
  for (int s = 0; s < 10; ++s) { bv[s] = -__builtin_inff(); bi[s] = 0xFFFFFFFFu; }

  uint32_t tb0 = (uint32_t)n * (uint32_t)KC + (uint32_t)base;
#pragma unroll 1
  for (int j = 0; j < 16; ++j) {
    float lgj = srow[j];                 // L1-hot scalar reload
    uint32_t kk = (uint32_t)(base + j);
    if (kk == 0u) lgj = -__builtin_inff();  // code 0 disallowed
    float mj = 0.69314718056f * __expf(lmax - lgj);
    uint32_t t0 = tb0 + (uint32_t)j;
#pragma unroll
    for (int sp = 0; sp < 5; ++sp) {
      uint32_t ba, bb;
      threefry_x2(t0 + (uint32_t)(2 * sp) * NKPROD,
                  t0 + (uint32_t)(2 * sp + 1) * NKPROD, ba, bb);
      float fa = __uint_as_float((ba >> 9) | 0x3F800000u) - 1.0f;
      float fb = __uint_as_float((bb >> 9) | 0x3F800000u) - 1.0f;
      float ua = fmaxf(1.17549435e-38f, fa);
      float ub = fmaxf(1.17549435e-38f, fb);
      float va = __log2f(ua) * mj;
      float vb = __log2f(ub) * mj;
      if (va > bv[2 * sp])     { bv[2 * sp] = va;     bi[2 * sp] = kk; }
      if (vb > bv[2 * sp + 1]) { bv[2 * sp + 1] = vb; bi[2 * sp + 1] = kk; }
    }
  }

  // wave argmax per draw (first-index tiebreak)
#pragma unroll
  for (int s = 0; s < 10; ++s) {
#pragma unroll
    for (int off = 32; off; off >>= 1) {
      float ov = __shfl_xor(bv[s], off, 64);
      uint32_t oi = __shfl_xor(bi[s], off, 64);
      if (ov > bv[s] || (ov == bv[s] && oi < bi[s])) { bv[s] = ov; bi[s] = oi; }
    }
  }

  // counts (transient; overwrites this row's logits)
  float* so = sout + (size_t)n * KC + base;
#pragma unroll
  for (int j4 = 0; j4 < 16; j4 += 4) {
    float c[4];
#pragma unroll
    for (int i = 0; i < 4; ++i) {
      uint32_t k = (uint32_t)(base + j4 + i);
      float cc = 0.f;
#pragma unroll
      for (int s = 0; s < 10; ++s) cc += (bi[s] == k) ? 1.f : 0.f;
      c[i] = cc;
    }
    *(float4*)(so + j4) = make_float4(c[0], c[1], c[2], c[3]);
  }

  // quantized gather (bi wave-uniform; codebook L2-hot) + ST + loss
  float q[8];
#pragma unroll
  for (int i = 0; i < 8; ++i) q[i] = 0.f;
#pragma unroll
  for (int s = 0; s < 10; ++s) {
    const float* cr = CW + (size_t)bi[s] * DM + l * 8;
    float4 g0 = *(const float4*)cr;
    float4 g1 = *(const float4*)(cr + 4);
    q[0] += g0.x; q[1] += g0.y; q[2] += g0.z; q[3] += g0.w;
    q[4] += g1.x; q[5] += g1.y; q[6] += g1.z; q[7] += g1.w;
    if (l == 0) atomicAdd(&cnt[bi[s]], 1.0f);
  }

  const float* xr = X + (size_t)n * DM + l * 8;
  float4 x0 = *(const float4*)xr, x1 = *(const float4*)(xr + 4);
  float xs[8] = {x0.x, x0.y, x0.z, x0.w, x1.x, x1.y, x1.z, x1.w};
  float st[8];
  double ls = 0.0;
#pragma unroll
  for (int j = 0; j < 8; ++j) {
    float qq = q[j] / 10.0f;
    float d = qq - xs[j];
    ls += (double)(d * d);
    st[j] = xs[j] + d;
  }
  float* qo = qout + (size_t)n * DM + l * 8;
  *(float4*)qo       = make_float4(st[0], st[1], st[2], st[3]);
  *(float4*)(qo + 4) = make_float4(st[4], st[5], st[6], st[7]);

#pragma unroll
  for (int off = 32; off; off >>= 1) ls += __shfl_xor(ls, off, 64);
  if (l == 0) atomicAdd(&esum[n & 63], ls);   // 64 striped slots
}

// ---------------- scalars: loss + perplexity ----------------
__global__ __launch_bounds__(256) void k_final(const int* __restrict__ npp,
                                               const float* __restrict__ cnt,
                                               const double* __restrict__ esum,
                                               float* __restrict__ scal) {
  __shared__ double snd[256];
  int t = threadIdx.x;
  int npad = NROWS - *npp;
  double ss = 0.0;
  for (int k = t; k < KC; k += 256) {
    float c = (k == 0) ? (float)(npad * 10) : cnt[k];
    float p = c / 327680.0f;   // / (N * NUM_SAMPLES)
    ss += (double)(p * logf(p + 1e-10f));
  }
  snd[t] = ss;
  __syncthreads();
  for (int off = 128; off; off >>= 1) {
    if (t < off) snd[t] += snd[t + off];
    __syncthreads();
  }
  if (t == 0) {
    double es = 0.0;
    for (int i = 0; i < 64; ++i) es += esum[i];
    float num_nonpad = (float)((NROWS - npad) * DM);
    float el = (float)es / num_nonpad;
    scal[0] = 0.25f * el;               // loss
    scal[1] = expf(-(float)snd[0]);     // perplexity
  }
}

extern "C" void kernel_launch(void* const* d_in, const int* in_sizes, int n_in,
                              void* d_out, int out_size, void* d_ws, size_t ws_size,
                              hipStream_t stream) {
  const float* X  = (const float*)d_in[0];
  const void*  M  = d_in[1];
  const float* CW = (const float*)d_in[2];
  float* out  = (float*)d_out;
  float* qout = out;                    // [0, 16777216): quantized_st
  float* sout = out + 16777216;         // [.., 50331648): logits -> samples
  float* scal = out + 50331648;         // loss, perplexity
  // A pre-split (by compact slot) occupies the qout region EXACTLY
  // (32768*512*2B*2 = 67,108,864 B); every byte rewritten by sampler/pad waves.
  _Float16* Ah2 = (_Float16*)qout;
  _Float16* Al2 = Ah2 + 16777216;
  uint8_t* ws = (uint8_t*)d_ws;
  double*   esum = (double*)ws;           // 512 B (64 striped slots)
  uint32_t* flag = (uint32_t*)(ws + 512);
  int*      npp  = (int*)(ws + 768);
  float*    cnt  = (float*)(ws + 1024);   // 4 KB per-code totals
  int*      cntB = (int*)(ws + 5120);     // 256 B per-block counts (bool interp)
  int*      cntI = (int*)(ws + 5376);     // 256 B per-block counts (int interp)
  int*      idx  = (int*)(ws + 8192);     // 128 KB: nonpad [0,NP) + pad [NP,32768)
  float*    An   = (float*)(ws + 139264); // 128 KB: A row norms by slot
  _Float16* Bh2  = (_Float16*)(ws + 270336);          // 1 MiB
  _Float16* Bl2  = (_Float16*)(ws + 270336 + 1048576);// 1 MiB
  float*    Bn   = (float*)(ws + 270336 + 2097152);   // 4 KB
  (void)in_sizes; (void)n_in; (void)out_size; (void)ws_size;

  hipMemsetAsync(d_ws, 0, 8192, stream);   // esum + flag + npp + cnt
  k_count_bsplit<<<320, 256, 0, stream>>>((const uint8_t*)M, CW, flag, cntB, cntI,
                                          Bh2, Bl2, Bn);
  k_scatter<<<64, 256, 0, stream>>>((const uint8_t*)M, flag, cntB, cntI, idx, npp);
  k_asplit_pad<<<8192, 256, 0, stream>>>(X, idx, npp, Ah2, Al2, An, sout, esum);
  k_gemm5<<<2048, 256, 0, stream>>>(Ah2, Al2, An, Bh2, Bl2, Bn, idx, npp, sout);
  k_sample_i<<<8192, 256, 0, stream>>>(sout, X, CW, idx, npp, qout, sout, cnt, esum);
  k_final<<<1, 256, 0, stream>>>(npp, cnt, esum, scal);
}